// Round 13
// baseline (345.414 us; speedup 1.0000x reference)
//
#include <hip/hip_runtime.h>

// BiPointNet fused v13: ONE persistent kernel at FULL occupancy.
// 256-thr blocks, __launch_bounds__(256,8) => <=64 VGPR => 8 blocks/CU =>
// 2048 co-resident blocks (8192 waves = 1 row/wave). Software grid barriers
// + agent-scope packed BN-stat atomics (R9/R10-proven). Weight masks live in
// LDS and are re-loaded per phase to cap register pressure. Occupancy-derived
// grid with a 2-row fallback instantiation removes deadlock risk.

typedef unsigned long long u64;
typedef unsigned int u32;

#define P_TOTAL (8192 * 32)
#define NREP 16

__device__ __forceinline__ u64 bcast64(u64 x, int p) {
    unsigned lo = __builtin_amdgcn_readlane((unsigned)x, p);
    unsigned hi = __builtin_amdgcn_readlane((unsigned)(x >> 32), p);
    return ((u64)hi << 32) | lo;
}

__device__ __forceinline__ u64 pack_stats(int sd, int sq) {
    return ((u64)(unsigned)sd << 32) | (u64)(unsigned)sq;
}

__device__ __forceinline__ void stat_add(u64* p, u64 v) {
    __hip_atomic_fetch_add(p, v, __ATOMIC_RELEASE, __HIP_MEMORY_SCOPE_AGENT);
}

// sum NREP replicas (agent-scope loads), fold BN+scale+gamma+beta -> a*dot+b
__device__ __forceinline__ void affine_from_stats(u64* st, int c,
        const float* __restrict__ scale, const float* __restrict__ gamma,
        const float* __restrict__ beta, int cparam, float& a, float& b) {
    u64 v = 0;
    #pragma unroll
    for (int r = 0; r < NREP; ++r)
        v += __hip_atomic_load(&st[r * 256 + c], __ATOMIC_RELAXED, __HIP_MEMORY_SCOPE_AGENT);
    int sd = (int)(v >> 32);
    int sq = (int)(unsigned)(v & 0xFFFFFFFFull);
    const double invN = 1.0 / (double)P_TOTAL;
    double m = (double)sd * invN;
    double var = (double)sq * invN - m * m;
    double sc = (double)scale[cparam];
    double inv = 1.0 / sqrt(sc * sc * var + 1e-5);
    double g = (double)gamma[cparam];
    a = (float)(g * inv * sc);
    b = (float)((double)beta[cparam] - g * inv * sc * m);
}

// integer threshold: fmaf(a,(float)d,b)>0 <=> (flip? -d : d) >= T. Exact.
__device__ __forceinline__ int make_thresh(float a, float b, bool& flip) {
    if (a == 0.f) { flip = false; return (b > 0.f) ? -65 : 65; }
    double r = -(double)b / (double)a;
    r = fmin(fmax(r, -1e6), 1e6);
    int t0 = (int)floor(r);
    int T;
    if (a > 0.f) {
        flip = false;
        T = t0 + 2;
        if (fmaf(a, (float)(t0 + 1), b) > 0.f) T = t0 + 1;
        if (fmaf(a, (float)(t0    ), b) > 0.f) T = t0;
        if (fmaf(a, (float)(t0 - 1), b) > 0.f) T = t0 - 1;
    } else {
        flip = true;
        int H = t0 - 2;
        if (fmaf(a, (float)(t0 - 1), b) > 0.f) H = t0 - 1;
        if (fmaf(a, (float)(t0    ), b) > 0.f) H = t0;
        if (fmaf(a, (float)(t0 + 1), b) > 0.f) H = t0 + 1;
        T = -H;
    }
    return max(-65, min(65, T));
}

// software grid barrier: counter k zeroed per call; release-inc + acquire-spin
__device__ __forceinline__ void gbar(u32* bar, int k, u32 nblk) {
    __syncthreads();
    if (threadIdx.x == 0) {
        __hip_atomic_fetch_add(&bar[k], 1u, __ATOMIC_ACQ_REL, __HIP_MEMORY_SCOPE_AGENT);
        while (__hip_atomic_load(&bar[k], __ATOMIC_ACQUIRE, __HIP_MEMORY_SCOPE_AGENT) < nblk)
            __builtin_amdgcn_s_sleep(2);
    }
    __syncthreads();
}

__global__ void k_zero(u64* __restrict__ stats, u32* __restrict__ bar) {
    stats[blockIdx.x * 256 + threadIdx.x] = 0;
    if (blockIdx.x == 0 && threadIdx.x < 16) bar[threadIdx.x] = 0;
}

template <int ROWS, int MINW>
__global__ void __launch_bounds__(256, MINW) kfused(
    const float4* __restrict__ in4,
    const float* __restrict__ W1, const float* __restrict__ s1,
    const float* __restrict__ g1, const float* __restrict__ b1,
    const float* __restrict__ W2, const float* __restrict__ s2,
    const float* __restrict__ g2, const float* __restrict__ b2,
    const float* __restrict__ W3, const float* __restrict__ s3,
    const float* __restrict__ g3, const float* __restrict__ b3,
    float* __restrict__ out, u64* __restrict__ stats, u32* __restrict__ bar) {
    const int lane = threadIdx.x & 63;
    const int wib = threadIdx.x >> 6;              // 0..3
    const u32 nblk = gridDim.x;
    const int TOTW = (int)nblk * 4;
    const int gw = (int)blockIdx.x * 4 + wib;
    const int rep = ((int)blockIdx.x & (NREP - 1)) * 256;

    __shared__ u64 wlds[512];                      // 4 KB weight masks
    __shared__ int redA[4][64], redB[4][64], redC[4][64], redD[4][64];  // 4 KB
    __shared__ int gT[64], gF[64];
    __shared__ float sA[128], sB[128];

    // ---- pack weight masks into LDS (one row per thread) ------------------
    {
        const int t = threadIdx.x;
        const float* src; int dstoff; bool perm, l1m;
        if (t < 64)       { src = W1 + t * 64;         dstoff = 2 * t;               perm = true;  l1m = true;  }
        else if (t < 128) { src = W2 + (t - 64) * 64;  dstoff = 128 + 2 * (t - 64);  perm = false; l1m = false; }
        else              { src = W3 + (t - 128) * 64; dstoff = 256 + 2 * (t - 128); perm = false; l1m = false; }
        const float4* s4 = (const float4*)src;
        u64 hiM = 0, loM = 0;
        #pragma unroll
        for (int j = 0; j < 16; ++j) {
            float4 v = s4[j];
            #pragma unroll
            for (int k = 0; k < 4; ++k) {
                const float w = (k == 0) ? v.x : (k == 1) ? v.y : (k == 2) ? v.z : v.w;
                const int c = 4 * j + k;
                const int p = perm ? (((c & 3) << 4) | (c >> 2)) : c;   // ballot perm
                const bool bh = (w > 0.f);
                const bool bl = l1m ? (w != 0.f) : (w < 0.f);
                if (bh) hiM |= 1ull << p;
                if (bl) loM |= 1ull << p;
            }
        }
        wlds[dstoff] = hiM;
        wlds[dstoff + 1] = loM;   // (sign,nz) L1; (pos,neg) L2/L3
    }
    __syncthreads();

    int rows[ROWS];
    bool hv[ROWS];
    #pragma unroll
    for (int k = 0; k < ROWS; ++k) { rows[k] = gw + k * TOTW; hv[k] = rows[k] < 8192; }

    // ---- phase 1: stream input (two 4-deep batches/row), A1 masks, stats1 --
    u64 a1s[ROWS], a1n[ROWS];
    {
        const u64 w1S = wlds[2 * lane], w1N = wlds[2 * lane + 1];
        int sd = 0, sq = 0;
        #pragma unroll
        for (int k = 0; k < ROWS; ++k) {
            a1s[k] = 0; a1n[k] = 0;
            if (hv[k]) {                            // wave-uniform predicate
                const size_t base = (size_t)rows[k] * 512 + lane;
                auto proc = [&](float4 v, int b, u64& ms, u64& mn) {
                    u64 bs0 = __ballot(v.x > 0.f), bn0 = __ballot(v.x != 0.f);
                    u64 bs1 = __ballot(v.y > 0.f), bn1 = __ballot(v.y != 0.f);
                    u64 bs2 = __ballot(v.z > 0.f), bn2 = __ballot(v.z != 0.f);
                    u64 bs3 = __ballot(v.w > 0.f), bn3 = __ballot(v.w != 0.f);
                    #pragma unroll
                    for (int p = 0; p < 4; ++p) {   // wave-uniform slices
                        const int s2 = p << 4;
                        u64 as = ((bs0 >> s2) & 0xFFFFull) | (((bs1 >> s2) & 0xFFFFull) << 16)
                               | (((bs2 >> s2) & 0xFFFFull) << 32) | (((bs3 >> s2) & 0xFFFFull) << 48);
                        u64 an = ((bn0 >> s2) & 0xFFFFull) | (((bn1 >> s2) & 0xFFFFull) << 16)
                               | (((bn2 >> s2) & 0xFFFFull) << 32) | (((bn3 >> s2) & 0xFFFFull) << 48);
                        u64 mnz = an & w1N;
                        int dot = __popcll(mnz) - 2 * __popcll(mnz & (as ^ w1S));
                        sd += dot; sq += dot * dot;
                        if (lane == b * 4 + p) { ms = as; mn = an; }
                    }
                };
                #pragma unroll
                for (int half = 0; half < 2; ++half) {
                    const size_t hb = base + (size_t)half * 256;
                    float4 v0 = in4[hb];
                    float4 v1 = in4[hb + 64];
                    float4 v2 = in4[hb + 128];
                    float4 v3 = in4[hb + 192];
                    proc(v0, half * 4 + 0, a1s[k], a1n[k]);
                    proc(v1, half * 4 + 1, a1s[k], a1n[k]);
                    proc(v2, half * 4 + 2, a1s[k], a1n[k]);
                    proc(v3, half * 4 + 3, a1s[k], a1n[k]);
                }
            }
        }
        redA[wib][lane] = sd; redB[wib][lane] = sq;
        __syncthreads();
        if (threadIdx.x < 64) {
            int td = redA[0][lane] + redA[1][lane] + redA[2][lane] + redA[3][lane];
            int tq = redB[0][lane] + redB[1][lane] + redB[2][lane] + redB[3][lane];
            stat_add(&stats[rep + lane], pack_stats(td, tq));
            __threadfence();
        }
    }
    gbar(bar, 0, nblk);

    // ---- phase 2: layer-1 binarize (int thresh) -> A2 regs, stats2 --------
    if (threadIdx.x < 64) {
        float a, b;
        affine_from_stats(stats, threadIdx.x, s1, g1, b1, threadIdx.x, a, b);
        bool fl;
        gT[threadIdx.x] = make_thresh(a, b, fl);
        gF[threadIdx.x] = fl ? 1 : 0;
    }
    __syncthreads();
    u64 a2m[ROWS];
    {
        const int T = gT[lane];
        const u64 w1N = wlds[2 * lane + 1];
        const u64 w1Sf = gF[lane] ? ~wlds[2 * lane] : wlds[2 * lane];   // flip => -dot
        const u64 w2P = wlds[128 + 2 * lane], w2N = wlds[129 + 2 * lane];
        int sd = 0, sq = 0;
        #pragma unroll
        for (int k = 0; k < ROWS; ++k) {
            a2m[k] = 0;
            if (hv[k]) {
                u64 mymask = 0;
                #pragma unroll 8
                for (int p = 0; p < 32; ++p) {
                    u64 as = bcast64(a1s[k], p);
                    u64 an = bcast64(a1n[k], p);
                    u64 mnz = an & w1N;
                    int dot1 = __popcll(mnz) - 2 * __popcll(mnz & (as ^ w1Sf));
                    u64 A = __ballot(dot1 >= T);
                    if (lane == p) mymask = A;
                    int d2 = __popcll(A & w2P) - __popcll(A & w2N);
                    sd += d2; sq += d2 * d2;
                }
                a2m[k] = mymask;
            }
        }
        __syncthreads();
        redA[wib][lane] = sd; redB[wib][lane] = sq;
        __syncthreads();
        if (threadIdx.x < 64) {
            int td = redA[0][lane] + redA[1][lane] + redA[2][lane] + redA[3][lane];
            int tq = redB[0][lane] + redB[1][lane] + redB[2][lane] + redB[3][lane];
            stat_add(&stats[rep + 64 + lane], pack_stats(td, tq));
            __threadfence();
        }
    }
    gbar(bar, 1, nblk);

    // ---- phase 3: layer-2 binarize, layer-3 dots -> stats3 + row max/min --
    if (threadIdx.x < 64) {
        float a, b;
        affine_from_stats(stats, 64 + threadIdx.x, s2, g2, b2, threadIdx.x, a, b);
        bool fl;
        gT[threadIdx.x] = make_thresh(a, b, fl);
        gF[threadIdx.x] = fl ? 1 : 0;
    }
    __syncthreads();
    int mxa[ROWS], mna[ROWS], mxb[ROWS], mnb[ROWS];
    {
        const int T = gT[lane];
        const u64 w2Pf = gF[lane] ? wlds[129 + 2 * lane] : wlds[128 + 2 * lane];
        const u64 w2Nf = gF[lane] ? wlds[128 + 2 * lane] : wlds[129 + 2 * lane];
        const u64 w3aP = wlds[256 + 2 * lane], w3aN = wlds[257 + 2 * lane];
        const u64 w3bP = wlds[256 + 2 * (lane + 64)], w3bN = wlds[257 + 2 * (lane + 64)];
        int sda = 0, sqa = 0, sdb = 0, sqb = 0;
        #pragma unroll
        for (int k = 0; k < ROWS; ++k) {
            int xa = -127, na = 127, xb = -127, nb = 127;
            if (hv[k]) {
                #pragma unroll 8
                for (int p = 0; p < 32; ++p) {
                    u64 A = bcast64(a2m[k], p);
                    int d2 = __popcll(A & w2Pf) - __popcll(A & w2Nf);
                    u64 A3 = __ballot(d2 >= T);
                    int da = __popcll(A3 & w3aP) - __popcll(A3 & w3aN);
                    int db = __popcll(A3 & w3bP) - __popcll(A3 & w3bN);
                    sda += da; sqa += da * da; sdb += db; sqb += db * db;
                    xa = max(xa, da); na = min(na, da);
                    xb = max(xb, db); nb = min(nb, db);
                }
            }
            mxa[k] = xa; mna[k] = na; mxb[k] = xb; mnb[k] = nb;
        }
        __syncthreads();
        redA[wib][lane] = sda; redB[wib][lane] = sqa;
        redC[wib][lane] = sdb; redD[wib][lane] = sqb;
        __syncthreads();
        if (threadIdx.x < 64) {
            int tda = redA[0][lane] + redA[1][lane] + redA[2][lane] + redA[3][lane];
            int tqa = redB[0][lane] + redB[1][lane] + redB[2][lane] + redB[3][lane];
            int tdb = redC[0][lane] + redC[1][lane] + redC[2][lane] + redC[3][lane];
            int tqb = redD[0][lane] + redD[1][lane] + redD[2][lane] + redD[3][lane];
            stat_add(&stats[rep + 128 + lane], pack_stats(tda, tqa));
            stat_add(&stats[rep + 192 + lane], pack_stats(tdb, tqb));
            __threadfence();
        }
    }
    gbar(bar, 2, nblk);

    // ---- phase 4: v = a*(a>=0?dmax:dmin)+b, ReLU, write [8192,128] --------
    if (threadIdx.x < 128) {
        affine_from_stats(stats, 128 + threadIdx.x, s3, g3, b3, threadIdx.x,
                          sA[threadIdx.x], sB[threadIdx.x]);
    }
    __syncthreads();
    {
        const float aa = sA[lane], ba = sB[lane];
        const float ab = sA[64 + lane], bb = sB[64 + lane];
        #pragma unroll
        for (int k = 0; k < ROWS; ++k) {
            if (hv[k]) {
                float va = fmaf(aa, (float)(aa >= 0.f ? mxa[k] : mna[k]), ba);
                float vb = fmaf(ab, (float)(ab >= 0.f ? mxb[k] : mnb[k]), bb);
                out[(size_t)rows[k] * 128 + lane] = fmaxf(va, 0.f);
                out[(size_t)rows[k] * 128 + 64 + lane] = fmaxf(vb, 0.f);
            }
        }
    }
}

extern "C" void kernel_launch(void* const* d_in, const int* in_sizes, int n_in,
                              void* d_out, int out_size, void* d_ws, size_t ws_size,
                              hipStream_t stream) {
    const float4* in4 = (const float4*)d_in[0];
    const float* W1 = (const float*)d_in[1];
    const float* s1 = (const float*)d_in[2];
    const float* g1 = (const float*)d_in[3];
    const float* b1 = (const float*)d_in[4];
    const float* W2 = (const float*)d_in[5];
    const float* s2 = (const float*)d_in[6];
    const float* g2 = (const float*)d_in[7];
    const float* b2 = (const float*)d_in[8];
    const float* W3 = (const float*)d_in[9];
    const float* s3 = (const float*)d_in[10];
    const float* g3 = (const float*)d_in[11];
    const float* b3 = (const float*)d_in[12];
    float* out = (float*)d_out;
    u64* stats = (u64*)d_ws;                       // 16 reps x 256 u64 = 32 KB
    u32* bar = (u32*)((char*)d_ws + 32768);

    k_zero<<<16, 256, 0, stream>>>(stats, bar);

    int occ1 = 0;
    (void)hipOccupancyMaxActiveBlocksPerMultiprocessor(
        &occ1, reinterpret_cast<const void*>(&kfused<1, 8>), 256, 0);
    if (occ1 >= 8) {
        kfused<1, 8><<<2048, 256, 0, stream>>>(in4, W1, s1, g1, b1, W2, s2, g2, b2,
                                               W3, s3, g3, b3, out, stats, bar);
    } else {
        // fallback: 2 rows/wave, 4 blocks/CU co-resident (128-VGPR bound)
        kfused<2, 4><<<1024, 256, 0, stream>>>(in4, W1, s1, g1, b1, W2, s2, g2, b2,
                                               W3, s3, g3, b3, out, stats, bar);
    }
}

// Round 14
// 83.404 us; speedup vs baseline: 4.1415x; 4.1415x over previous
//
#include <hip/hip_runtime.h>

// BiPointNet v14: R7 split pipeline (proven 72us) minus k0: weight masks are
// packed per-block into LDS (parallel, L2-cached W reads), BN params computed
// by a spare wave in the same preamble, stats zeroed by hipMemsetAsync.
// k2/k3: full unroll + dual accumulators for shorter dep chains.

typedef unsigned long long u64;
typedef unsigned int u32;

#define P_TOTAL (8192 * 32)
#define NREP 16

__device__ __forceinline__ u64 bcast64(u64 x, int p) {
    unsigned lo = __builtin_amdgcn_readlane((unsigned)x, p);
    unsigned hi = __builtin_amdgcn_readlane((unsigned)(x >> 32), p);
    return ((u64)hi << 32) | lo;
}

__device__ __forceinline__ u64 pack_stats(int sd, int sq) {
    return ((u64)(unsigned)sd << 32) | (u64)(unsigned)sq;
}

// sum NREP replicas, fold BN+scale+gamma+beta -> v = a*dot + b
__device__ __forceinline__ void affine_from_stats(const u64* __restrict__ st,
        int c, const float* __restrict__ scale, const float* __restrict__ gamma,
        const float* __restrict__ beta, int cparam, float& a, float& b) {
    u64 v = 0;
    #pragma unroll
    for (int r = 0; r < NREP; ++r) v += st[r * 256 + c];
    int sd = (int)(v >> 32);
    int sq = (int)(unsigned)(v & 0xFFFFFFFFull);
    const double invN = 1.0 / (double)P_TOTAL;
    double m = (double)sd * invN;
    double var = (double)sq * invN - m * m;
    double sc = (double)scale[cparam];
    double inv = 1.0 / sqrt(sc * sc * var + 1e-5);
    double g = (double)gamma[cparam];
    a = (float)(g * inv * sc);
    b = (float)((double)beta[cparam] - g * inv * sc * m);
}

// integer threshold: fmaf(a,(float)d,b)>0 <=> (flip? -d : d) >= T. Exact.
__device__ __forceinline__ int make_thresh(float a, float b, bool& flip) {
    if (a == 0.f) { flip = false; return (b > 0.f) ? -65 : 65; }
    double r = -(double)b / (double)a;
    r = fmin(fmax(r, -1e6), 1e6);
    int t0 = (int)floor(r);
    int T;
    if (a > 0.f) {
        flip = false;
        T = t0 + 2;
        if (fmaf(a, (float)(t0 + 1), b) > 0.f) T = t0 + 1;
        if (fmaf(a, (float)(t0    ), b) > 0.f) T = t0;
        if (fmaf(a, (float)(t0 - 1), b) > 0.f) T = t0 - 1;
    } else {
        flip = true;
        int H = t0 - 2;
        if (fmaf(a, (float)(t0 - 1), b) > 0.f) H = t0 - 1;
        if (fmaf(a, (float)(t0    ), b) > 0.f) H = t0;
        if (fmaf(a, (float)(t0 + 1), b) > 0.f) H = t0 + 1;
        T = -H;
    }
    return max(-65, min(65, T));
}

// pack one weight row (64 floats) into (hi,lo) masks.
// l1m: hi=sign(perm'd), lo=nonzero.  else: hi=pos, lo=neg. perm for k1 ballots.
__device__ __forceinline__ void pack_row(const float* __restrict__ src, bool perm,
                                         bool l1m, u64& hiM, u64& loM) {
    const float4* s4 = (const float4*)src;
    hiM = 0; loM = 0;
    #pragma unroll
    for (int j = 0; j < 16; ++j) {
        float4 v = s4[j];
        #pragma unroll
        for (int k = 0; k < 4; ++k) {
            const float w = (k == 0) ? v.x : (k == 1) ? v.y : (k == 2) ? v.z : v.w;
            const int c = 4 * j + k;
            const int p = perm ? (((c & 3) << 4) | (c >> 2)) : c;
            const bool bh = (w > 0.f);
            const bool bl = l1m ? (w != 0.f) : (w < 0.f);
            if (bh) hiM |= 1ull << p;
            if (bl) loM |= 1ull << p;
        }
    }
}

// ------------- K1: input pack (ballots) + layer-1 dot stats -----------------
// 2048 blocks, 8192 waves x 32 positions; all 8 float4 loads issued up front.
__global__ void __launch_bounds__(256) k1_pack_stats(
    const float4* __restrict__ in4, const float* __restrict__ W1,
    ulonglong2* __restrict__ A1, u64* __restrict__ stats) {
    __shared__ u64 wl[128];
    if (threadIdx.x < 64) {
        u64 h, l;
        pack_row(W1 + threadIdx.x * 64, true, true, h, l);
        wl[2 * threadIdx.x] = h;
        wl[2 * threadIdx.x + 1] = l;
    }
    __syncthreads();

    const int lane = threadIdx.x & 63;
    const int wib = threadIdx.x >> 6;
    const int wid = (blockIdx.x << 2) | wib;
    const u64 w1S = wl[2 * lane], w1N = wl[2 * lane + 1];
    const int sh = (lane >> 4) << 4;
    const size_t base = (size_t)wid * 512 + lane;   // 32 pos * 16 float4/pos

    float4 v0 = in4[base];
    float4 v1 = in4[base + 64];
    float4 v2 = in4[base + 128];
    float4 v3 = in4[base + 192];
    float4 v4 = in4[base + 256];
    float4 v5 = in4[base + 320];
    float4 v6 = in4[base + 384];
    float4 v7 = in4[base + 448];

    int sd = 0, sq = 0;
    auto proc = [&](float4 v, int q0) {
        u64 bs0 = __ballot(v.x > 0.f), bn0 = __ballot(v.x != 0.f);
        u64 bs1 = __ballot(v.y > 0.f), bn1 = __ballot(v.y != 0.f);
        u64 bs2 = __ballot(v.z > 0.f), bn2 = __ballot(v.z != 0.f);
        u64 bs3 = __ballot(v.w > 0.f), bn3 = __ballot(v.w != 0.f);
        u64 myS = ((bs0 >> sh) & 0xFFFFull) | (((bs1 >> sh) & 0xFFFFull) << 16)
                | (((bs2 >> sh) & 0xFFFFull) << 32) | (((bs3 >> sh) & 0xFFFFull) << 48);
        u64 myN = ((bn0 >> sh) & 0xFFFFull) | (((bn1 >> sh) & 0xFFFFull) << 16)
                | (((bn2 >> sh) & 0xFFFFull) << 32) | (((bn3 >> sh) & 0xFFFFull) << 48);
        if ((lane & 15) == 0) A1[q0 + (lane >> 4)] = make_ulonglong2(myS, myN);
        #pragma unroll
        for (int p = 0; p < 4; ++p) {               // wave-uniform slices
            const int s2 = p << 4;
            u64 as = ((bs0 >> s2) & 0xFFFFull) | (((bs1 >> s2) & 0xFFFFull) << 16)
                   | (((bs2 >> s2) & 0xFFFFull) << 32) | (((bs3 >> s2) & 0xFFFFull) << 48);
            u64 an = ((bn0 >> s2) & 0xFFFFull) | (((bn1 >> s2) & 0xFFFFull) << 16)
                   | (((bn2 >> s2) & 0xFFFFull) << 32) | (((bn3 >> s2) & 0xFFFFull) << 48);
            u64 mnz = an & w1N;
            int dot = __popcll(mnz) - 2 * __popcll(mnz & (as ^ w1S));
            sd += dot; sq += dot * dot;
        }
    };
    const int q_base = wid * 32;
    proc(v0, q_base);      proc(v1, q_base + 4);
    proc(v2, q_base + 8);  proc(v3, q_base + 12);
    proc(v4, q_base + 16); proc(v5, q_base + 20);
    proc(v6, q_base + 24); proc(v7, q_base + 28);

    __shared__ int rd[4][64], rq[4][64];
    rd[wib][lane] = sd; rq[wib][lane] = sq;
    __syncthreads();
    if (threadIdx.x < 64) {
        int td = rd[0][lane] + rd[1][lane] + rd[2][lane] + rd[3][lane];
        int tq = rq[0][lane] + rq[1][lane] + rq[2][lane] + rq[3][lane];
        atomicAdd(&stats[(blockIdx.x & (NREP - 1)) * 256 + lane], pack_stats(td, tq));
    }
}

// -------- K2: layer-1 binarize (int thresh) -> A2, layer-2 dot stats --------
// 2048 blocks, 8192 waves x 32 positions. Preamble: waves 0/1 pack W1/W2,
// wave 2 computes BN params — all before one __syncthreads().
__global__ void __launch_bounds__(256) k2_bin1_stats2(
    const ulonglong2* __restrict__ A1, const float* __restrict__ W1,
    const float* __restrict__ W2, const float* __restrict__ scale,
    const float* __restrict__ gamma, const float* __restrict__ beta,
    u64* __restrict__ A2, u64* __restrict__ stats) {
    __shared__ u64 wl[256];          // [0..127]=W1(perm,s/nz) [128..255]=W2(p/n)
    __shared__ int gT[64], gF[64];
    {
        const int t = threadIdx.x;
        if (t < 64) {
            u64 h, l;
            pack_row(W1 + t * 64, true, true, h, l);
            wl[2 * t] = h; wl[2 * t + 1] = l;
        } else if (t < 128) {
            u64 h, l;
            pack_row(W2 + (t - 64) * 64, false, false, h, l);
            wl[2 * t] = h; wl[2 * t + 1] = l;
        } else if (t < 192) {
            const int c = t - 128;
            float a, b;
            affine_from_stats(stats, c, scale, gamma, beta, c, a, b);
            bool fl;
            gT[c] = make_thresh(a, b, fl);
            gF[c] = fl ? 1 : 0;
        }
    }
    __syncthreads();

    const int lane = threadIdx.x & 63;
    const int wib = threadIdx.x >> 6;
    const int wid = (blockIdx.x << 2) | wib;        // 8192 waves x 32 positions
    const int T = gT[lane];
    const u64 w1S = gF[lane] ? ~wl[2 * lane] : wl[2 * lane];   // flip => -dot
    const u64 w1N = wl[2 * lane + 1];
    const u64 w2P = wl[128 + 2 * lane], w2N = wl[129 + 2 * lane];

    const u64 av = ((const u64*)A1)[(size_t)wid * 64 + lane];  // 32 pos x 2 u64
    u64 mymask = 0;
    int sd0 = 0, sq0 = 0, sd1 = 0, sq1 = 0;
    #pragma unroll
    for (int pp = 0; pp < 16; ++pp) {
        {   // even position 2pp
            const int p = 2 * pp;
            u64 as = bcast64(av, 2 * p);
            u64 an = bcast64(av, 2 * p + 1);
            u64 mnz = an & w1N;
            int dot1 = __popcll(mnz) - 2 * __popcll(mnz & (as ^ w1S));
            u64 A = __ballot(dot1 >= T);
            if (lane == p) mymask = A;
            int d2 = __popcll(A & w2P) - __popcll(A & w2N);
            sd0 += d2; sq0 += d2 * d2;
        }
        {   // odd position 2pp+1 (independent chain)
            const int p = 2 * pp + 1;
            u64 as = bcast64(av, 2 * p);
            u64 an = bcast64(av, 2 * p + 1);
            u64 mnz = an & w1N;
            int dot1 = __popcll(mnz) - 2 * __popcll(mnz & (as ^ w1S));
            u64 A = __ballot(dot1 >= T);
            if (lane == p) mymask = A;
            int d2 = __popcll(A & w2P) - __popcll(A & w2N);
            sd1 += d2; sq1 += d2 * d2;
        }
    }
    if (lane < 32) A2[(size_t)wid * 32 + lane] = mymask;

    __shared__ int rd[4][64], rq[4][64];
    rd[wib][lane] = sd0 + sd1; rq[wib][lane] = sq0 + sq1;
    __syncthreads();
    if (threadIdx.x < 64) {
        int td = rd[0][lane] + rd[1][lane] + rd[2][lane] + rd[3][lane];
        int tq = rq[0][lane] + rq[1][lane] + rq[2][lane] + rq[3][lane];
        atomicAdd(&stats[(blockIdx.x & (NREP - 1)) * 256 + 64 + lane], pack_stats(td, tq));
    }
}

// -- K3: layer-2 binarize (int thresh), layer-3 dots -> stats + row max/min --
// 2048 blocks, 8192 waves = one output row per wave.
__global__ void __launch_bounds__(256) k3_bin2_stats3(
    const u64* __restrict__ A2, const float* __restrict__ W2,
    const float* __restrict__ W3, const float* __restrict__ scale,
    const float* __restrict__ gamma, const float* __restrict__ beta,
    short* __restrict__ dmm, u64* __restrict__ stats) {
    __shared__ u64 wl[384];          // [0..127]=W2 [128..383]=W3 (128 rows)
    __shared__ int gT[64], gF[64];
    {
        const int t = threadIdx.x;
        if (t < 64) {
            u64 h, l;
            pack_row(W2 + t * 64, false, false, h, l);
            wl[2 * t] = h; wl[2 * t + 1] = l;
        } else if (t < 192) {
            const int r = t - 64;
            u64 h, l;
            pack_row(W3 + r * 64, false, false, h, l);
            wl[128 + 2 * r] = h; wl[129 + 2 * r] = l;
        } else {
            const int c = t - 192;
            float a, b;
            affine_from_stats(stats, 64 + c, scale, gamma, beta, c, a, b);
            bool fl;
            gT[c] = make_thresh(a, b, fl);
            gF[c] = fl ? 1 : 0;
        }
    }
    __syncthreads();

    const int lane = threadIdx.x & 63;
    const int wib = threadIdx.x >> 6;
    const int wid = (blockIdx.x << 2) | wib;        // row m = wid
    const int T = gT[lane];
    const u64 w2P = gF[lane] ? wl[2 * lane + 1] : wl[2 * lane];   // flip: swap
    const u64 w2N = gF[lane] ? wl[2 * lane] : wl[2 * lane + 1];
    const u64 w3aP = wl[128 + 2 * lane], w3aN = wl[129 + 2 * lane];
    const u64 w3bP = wl[128 + 2 * (lane + 64)], w3bN = wl[129 + 2 * (lane + 64)];

    const u32 a32 = ((const u32*)A2)[(size_t)wid * 64 + lane];  // 32 pos x 2 u32
    int sda0 = 0, sqa0 = 0, sdb0 = 0, sqb0 = 0;
    int sda1 = 0, sqa1 = 0, sdb1 = 0, sqb1 = 0;
    int maxa = -127, mina = 127, maxb = -127, minb = 127;
    #pragma unroll
    for (int pp = 0; pp < 16; ++pp) {
        {
            const int p = 2 * pp;
            u32 lo = __builtin_amdgcn_readlane(a32, 2 * p);
            u32 hi = __builtin_amdgcn_readlane(a32, 2 * p + 1);
            u64 A = ((u64)hi << 32) | lo;
            int d2 = __popcll(A & w2P) - __popcll(A & w2N);
            u64 A3 = __ballot(d2 >= T);
            int da = __popcll(A3 & w3aP) - __popcll(A3 & w3aN);
            int db = __popcll(A3 & w3bP) - __popcll(A3 & w3bN);
            sda0 += da; sqa0 += da * da; sdb0 += db; sqb0 += db * db;
            maxa = max(maxa, da); mina = min(mina, da);
            maxb = max(maxb, db); minb = min(minb, db);
        }
        {
            const int p = 2 * pp + 1;
            u32 lo = __builtin_amdgcn_readlane(a32, 2 * p);
            u32 hi = __builtin_amdgcn_readlane(a32, 2 * p + 1);
            u64 A = ((u64)hi << 32) | lo;
            int d2 = __popcll(A & w2P) - __popcll(A & w2N);
            u64 A3 = __ballot(d2 >= T);
            int da = __popcll(A3 & w3aP) - __popcll(A3 & w3aN);
            int db = __popcll(A3 & w3bP) - __popcll(A3 & w3bN);
            sda1 += da; sqa1 += da * da; sdb1 += db; sqb1 += db * db;
            maxa = max(maxa, da); mina = min(mina, da);
            maxb = max(maxb, db); minb = min(minb, db);
        }
    }
    dmm[wid * 128 + lane]      = (short)((maxa & 0xFF) | ((mina & 0xFF) << 8));
    dmm[wid * 128 + 64 + lane] = (short)((maxb & 0xFF) | ((minb & 0xFF) << 8));

    __shared__ int rda[4][64], rqa[4][64], rdb[4][64], rqb[4][64];
    rda[wib][lane] = sda0 + sda1; rqa[wib][lane] = sqa0 + sqa1;
    rdb[wib][lane] = sdb0 + sdb1; rqb[wib][lane] = sqb0 + sqb1;
    __syncthreads();
    if (threadIdx.x < 64) {
        const int rep = (blockIdx.x & (NREP - 1)) * 256;
        int tda = rda[0][lane] + rda[1][lane] + rda[2][lane] + rda[3][lane];
        int tqa = rqa[0][lane] + rqa[1][lane] + rqa[2][lane] + rqa[3][lane];
        int tdb = rdb[0][lane] + rdb[1][lane] + rdb[2][lane] + rdb[3][lane];
        int tqb = rqb[0][lane] + rqb[1][lane] + rqb[2][lane] + rqb[3][lane];
        atomicAdd(&stats[rep + 128 + lane], pack_stats(tda, tqa));
        atomicAdd(&stats[rep + 192 + lane], pack_stats(tdb, tqb));
    }
}

// -------- K4: v = a*(a>=0?dmax:dmin)+b, ReLU, write [8192,128] --------------
__global__ void __launch_bounds__(512) k4_out(
    const short* __restrict__ dmm, const float* __restrict__ scale,
    const float* __restrict__ gamma, const float* __restrict__ beta,
    const u64* __restrict__ stats, float* __restrict__ out) {
    __shared__ float sa[128], sb[128];
    if (threadIdx.x < 128)
        affine_from_stats(stats, 128 + threadIdx.x, scale, gamma, beta,
                          threadIdx.x, sa[threadIdx.x], sb[threadIdx.x]);
    __syncthreads();
    const int idx = blockIdx.x * 512 + threadIdx.x;   // m*128 + o
    const int o = idx & 127;
    short pk = dmm[idx];
    int mx = (signed char)(pk & 0xFF);
    int mn = (signed char)((pk >> 8) & 0xFF);
    float a = sa[o], b = sb[o];
    float v = fmaf(a, (float)(a >= 0.f ? mx : mn), b);
    out[idx] = fmaxf(v, 0.f);
}

extern "C" void kernel_launch(void* const* d_in, const int* in_sizes, int n_in,
                              void* d_out, int out_size, void* d_ws, size_t ws_size,
                              hipStream_t stream) {
    const float* agg = (const float*)d_in[0];
    const float* W1 = (const float*)d_in[1];
    const float* s1 = (const float*)d_in[2];
    const float* g1 = (const float*)d_in[3];
    const float* b1 = (const float*)d_in[4];
    const float* W2 = (const float*)d_in[5];
    const float* s2 = (const float*)d_in[6];
    const float* g2 = (const float*)d_in[7];
    const float* b2 = (const float*)d_in[8];
    const float* W3 = (const float*)d_in[9];
    const float* s3 = (const float*)d_in[10];
    const float* g3 = (const float*)d_in[11];
    const float* b3 = (const float*)d_in[12];
    float* out = (float*)d_out;

    char* ws = (char*)d_ws;
    u64* stats = (u64*)ws;                                     // 32 KB
    ulonglong2* A1 = (ulonglong2*)(ws + 65536);                // 4 MB
    u64* A2 = (u64*)(ws + 65536 + (size_t)P_TOTAL * 16);       // 2 MB
    short* dmm = (short*)(ws + 65536 + (size_t)P_TOTAL * 24);  // 2 MB

    hipMemsetAsync(stats, 0, NREP * 256 * sizeof(u64), stream);
    k1_pack_stats<<<2048, 256, 0, stream>>>((const float4*)agg, W1, A1, stats);
    k2_bin1_stats2<<<2048, 256, 0, stream>>>(A1, W1, W2, s1, g1, b1, A2, stats);
    k3_bin2_stats3<<<2048, 256, 0, stream>>>(A2, W2, W3, s2, g2, b2, dmm, stats);
    k4_out<<<2048, 512, 0, stream>>>(dmm, s3, g3, b3, stats, out);
}

// Round 15
// 82.364 us; speedup vs baseline: 4.1937x; 1.0126x over previous
//
#include <hip/hip_runtime.h>

// BiPointNet v15: R14 pipeline (weight-pack preambles in LDS, dual-accumulator
// k2/k3 bodies) with hipMemsetAsync(stats) replaced by a tiny k_zero kernel —
// the runtime fill kernel cost a fixed ~39us inside the graph (R14 profile).

typedef unsigned long long u64;
typedef unsigned int u32;

#define P_TOTAL (8192 * 32)
#define NREP 16

__device__ __forceinline__ u64 bcast64(u64 x, int p) {
    unsigned lo = __builtin_amdgcn_readlane((unsigned)x, p);
    unsigned hi = __builtin_amdgcn_readlane((unsigned)(x >> 32), p);
    return ((u64)hi << 32) | lo;
}

__device__ __forceinline__ u64 pack_stats(int sd, int sq) {
    return ((u64)(unsigned)sd << 32) | (u64)(unsigned)sq;
}

// sum NREP replicas, fold BN+scale+gamma+beta -> v = a*dot + b
__device__ __forceinline__ void affine_from_stats(const u64* __restrict__ st,
        int c, const float* __restrict__ scale, const float* __restrict__ gamma,
        const float* __restrict__ beta, int cparam, float& a, float& b) {
    u64 v = 0;
    #pragma unroll
    for (int r = 0; r < NREP; ++r) v += st[r * 256 + c];
    int sd = (int)(v >> 32);
    int sq = (int)(unsigned)(v & 0xFFFFFFFFull);
    const double invN = 1.0 / (double)P_TOTAL;
    double m = (double)sd * invN;
    double var = (double)sq * invN - m * m;
    double sc = (double)scale[cparam];
    double inv = 1.0 / sqrt(sc * sc * var + 1e-5);
    double g = (double)gamma[cparam];
    a = (float)(g * inv * sc);
    b = (float)((double)beta[cparam] - g * inv * sc * m);
}

// integer threshold: fmaf(a,(float)d,b)>0 <=> (flip? -d : d) >= T. Exact.
__device__ __forceinline__ int make_thresh(float a, float b, bool& flip) {
    if (a == 0.f) { flip = false; return (b > 0.f) ? -65 : 65; }
    double r = -(double)b / (double)a;
    r = fmin(fmax(r, -1e6), 1e6);
    int t0 = (int)floor(r);
    int T;
    if (a > 0.f) {
        flip = false;
        T = t0 + 2;
        if (fmaf(a, (float)(t0 + 1), b) > 0.f) T = t0 + 1;
        if (fmaf(a, (float)(t0    ), b) > 0.f) T = t0;
        if (fmaf(a, (float)(t0 - 1), b) > 0.f) T = t0 - 1;
    } else {
        flip = true;
        int H = t0 - 2;
        if (fmaf(a, (float)(t0 - 1), b) > 0.f) H = t0 - 1;
        if (fmaf(a, (float)(t0    ), b) > 0.f) H = t0;
        if (fmaf(a, (float)(t0 + 1), b) > 0.f) H = t0 + 1;
        T = -H;
    }
    return max(-65, min(65, T));
}

// pack one weight row (64 floats) into (hi,lo) masks.
// l1m: hi=sign(perm'd), lo=nonzero.  else: hi=pos, lo=neg. perm for k1 ballots.
__device__ __forceinline__ void pack_row(const float* __restrict__ src, bool perm,
                                         bool l1m, u64& hiM, u64& loM) {
    const float4* s4 = (const float4*)src;
    hiM = 0; loM = 0;
    #pragma unroll
    for (int j = 0; j < 16; ++j) {
        float4 v = s4[j];
        #pragma unroll
        for (int k = 0; k < 4; ++k) {
            const float w = (k == 0) ? v.x : (k == 1) ? v.y : (k == 2) ? v.z : v.w;
            const int c = 4 * j + k;
            const int p = perm ? (((c & 3) << 4) | (c >> 2)) : c;
            const bool bh = (w > 0.f);
            const bool bl = l1m ? (w != 0.f) : (w < 0.f);
            if (bh) hiM |= 1ull << p;
            if (bl) loM |= 1ull << p;
        }
    }
}

// ---------------- k_zero: zero the 16-replica stat array -------------------
__global__ void k_zero(u64* __restrict__ stats) {
    stats[blockIdx.x * 256 + threadIdx.x] = 0;
}

// ------------- K1: input pack (ballots) + layer-1 dot stats -----------------
// 2048 blocks, 8192 waves x 32 positions; all 8 float4 loads issued up front.
__global__ void __launch_bounds__(256) k1_pack_stats(
    const float4* __restrict__ in4, const float* __restrict__ W1,
    ulonglong2* __restrict__ A1, u64* __restrict__ stats) {
    __shared__ u64 wl[128];
    if (threadIdx.x < 64) {
        u64 h, l;
        pack_row(W1 + threadIdx.x * 64, true, true, h, l);
        wl[2 * threadIdx.x] = h;
        wl[2 * threadIdx.x + 1] = l;
    }
    __syncthreads();

    const int lane = threadIdx.x & 63;
    const int wib = threadIdx.x >> 6;
    const int wid = (blockIdx.x << 2) | wib;
    const u64 w1S = wl[2 * lane], w1N = wl[2 * lane + 1];
    const int sh = (lane >> 4) << 4;
    const size_t base = (size_t)wid * 512 + lane;   // 32 pos * 16 float4/pos

    float4 v0 = in4[base];
    float4 v1 = in4[base + 64];
    float4 v2 = in4[base + 128];
    float4 v3 = in4[base + 192];
    float4 v4 = in4[base + 256];
    float4 v5 = in4[base + 320];
    float4 v6 = in4[base + 384];
    float4 v7 = in4[base + 448];

    int sd = 0, sq = 0;
    auto proc = [&](float4 v, int q0) {
        u64 bs0 = __ballot(v.x > 0.f), bn0 = __ballot(v.x != 0.f);
        u64 bs1 = __ballot(v.y > 0.f), bn1 = __ballot(v.y != 0.f);
        u64 bs2 = __ballot(v.z > 0.f), bn2 = __ballot(v.z != 0.f);
        u64 bs3 = __ballot(v.w > 0.f), bn3 = __ballot(v.w != 0.f);
        u64 myS = ((bs0 >> sh) & 0xFFFFull) | (((bs1 >> sh) & 0xFFFFull) << 16)
                | (((bs2 >> sh) & 0xFFFFull) << 32) | (((bs3 >> sh) & 0xFFFFull) << 48);
        u64 myN = ((bn0 >> sh) & 0xFFFFull) | (((bn1 >> sh) & 0xFFFFull) << 16)
                | (((bn2 >> sh) & 0xFFFFull) << 32) | (((bn3 >> sh) & 0xFFFFull) << 48);
        if ((lane & 15) == 0) A1[q0 + (lane >> 4)] = make_ulonglong2(myS, myN);
        #pragma unroll
        for (int p = 0; p < 4; ++p) {               // wave-uniform slices
            const int s2 = p << 4;
            u64 as = ((bs0 >> s2) & 0xFFFFull) | (((bs1 >> s2) & 0xFFFFull) << 16)
                   | (((bs2 >> s2) & 0xFFFFull) << 32) | (((bs3 >> s2) & 0xFFFFull) << 48);
            u64 an = ((bn0 >> s2) & 0xFFFFull) | (((bn1 >> s2) & 0xFFFFull) << 16)
                   | (((bn2 >> s2) & 0xFFFFull) << 32) | (((bn3 >> s2) & 0xFFFFull) << 48);
            u64 mnz = an & w1N;
            int dot = __popcll(mnz) - 2 * __popcll(mnz & (as ^ w1S));
            sd += dot; sq += dot * dot;
        }
    };
    const int q_base = wid * 32;
    proc(v0, q_base);      proc(v1, q_base + 4);
    proc(v2, q_base + 8);  proc(v3, q_base + 12);
    proc(v4, q_base + 16); proc(v5, q_base + 20);
    proc(v6, q_base + 24); proc(v7, q_base + 28);

    __shared__ int rd[4][64], rq[4][64];
    rd[wib][lane] = sd; rq[wib][lane] = sq;
    __syncthreads();
    if (threadIdx.x < 64) {
        int td = rd[0][lane] + rd[1][lane] + rd[2][lane] + rd[3][lane];
        int tq = rq[0][lane] + rq[1][lane] + rq[2][lane] + rq[3][lane];
        atomicAdd(&stats[(blockIdx.x & (NREP - 1)) * 256 + lane], pack_stats(td, tq));
    }
}

// -------- K2: layer-1 binarize (int thresh) -> A2, layer-2 dot stats --------
// 2048 blocks, 8192 waves x 32 positions. Preamble: waves 0/1 pack W1/W2,
// wave 2 computes BN params — all before one __syncthreads().
__global__ void __launch_bounds__(256) k2_bin1_stats2(
    const ulonglong2* __restrict__ A1, const float* __restrict__ W1,
    const float* __restrict__ W2, const float* __restrict__ scale,
    const float* __restrict__ gamma, const float* __restrict__ beta,
    u64* __restrict__ A2, u64* __restrict__ stats) {
    __shared__ u64 wl[256];          // [0..127]=W1(perm,s/nz) [128..255]=W2(p/n)
    __shared__ int gT[64], gF[64];
    {
        const int t = threadIdx.x;
        if (t < 64) {
            u64 h, l;
            pack_row(W1 + t * 64, true, true, h, l);
            wl[2 * t] = h; wl[2 * t + 1] = l;
        } else if (t < 128) {
            u64 h, l;
            pack_row(W2 + (t - 64) * 64, false, false, h, l);
            wl[2 * t] = h; wl[2 * t + 1] = l;
        } else if (t < 192) {
            const int c = t - 128;
            float a, b;
            affine_from_stats(stats, c, scale, gamma, beta, c, a, b);
            bool fl;
            gT[c] = make_thresh(a, b, fl);
            gF[c] = fl ? 1 : 0;
        }
    }
    __syncthreads();

    const int lane = threadIdx.x & 63;
    const int wib = threadIdx.x >> 6;
    const int wid = (blockIdx.x << 2) | wib;        // 8192 waves x 32 positions
    const int T = gT[lane];
    const u64 w1S = gF[lane] ? ~wl[2 * lane] : wl[2 * lane];   // flip => -dot
    const u64 w1N = wl[2 * lane + 1];
    const u64 w2P = wl[128 + 2 * lane], w2N = wl[129 + 2 * lane];

    const u64 av = ((const u64*)A1)[(size_t)wid * 64 + lane];  // 32 pos x 2 u64
    u64 mymask = 0;
    int sd0 = 0, sq0 = 0, sd1 = 0, sq1 = 0;
    #pragma unroll
    for (int pp = 0; pp < 16; ++pp) {
        {   // even position 2pp
            const int p = 2 * pp;
            u64 as = bcast64(av, 2 * p);
            u64 an = bcast64(av, 2 * p + 1);
            u64 mnz = an & w1N;
            int dot1 = __popcll(mnz) - 2 * __popcll(mnz & (as ^ w1S));
            u64 A = __ballot(dot1 >= T);
            if (lane == p) mymask = A;
            int d2 = __popcll(A & w2P) - __popcll(A & w2N);
            sd0 += d2; sq0 += d2 * d2;
        }
        {   // odd position 2pp+1 (independent chain)
            const int p = 2 * pp + 1;
            u64 as = bcast64(av, 2 * p);
            u64 an = bcast64(av, 2 * p + 1);
            u64 mnz = an & w1N;
            int dot1 = __popcll(mnz) - 2 * __popcll(mnz & (as ^ w1S));
            u64 A = __ballot(dot1 >= T);
            if (lane == p) mymask = A;
            int d2 = __popcll(A & w2P) - __popcll(A & w2N);
            sd1 += d2; sq1 += d2 * d2;
        }
    }
    if (lane < 32) A2[(size_t)wid * 32 + lane] = mymask;

    __shared__ int rd[4][64], rq[4][64];
    rd[wib][lane] = sd0 + sd1; rq[wib][lane] = sq0 + sq1;
    __syncthreads();
    if (threadIdx.x < 64) {
        int td = rd[0][lane] + rd[1][lane] + rd[2][lane] + rd[3][lane];
        int tq = rq[0][lane] + rq[1][lane] + rq[2][lane] + rq[3][lane];
        atomicAdd(&stats[(blockIdx.x & (NREP - 1)) * 256 + 64 + lane], pack_stats(td, tq));
    }
}

// -- K3: layer-2 binarize (int thresh), layer-3 dots -> stats + row max/min --
// 2048 blocks, 8192 waves = one output row per wave.
__global__ void __launch_bounds__(256) k3_bin2_stats3(
    const u64* __restrict__ A2, const float* __restrict__ W2,
    const float* __restrict__ W3, const float* __restrict__ scale,
    const float* __restrict__ gamma, const float* __restrict__ beta,
    short* __restrict__ dmm, u64* __restrict__ stats) {
    __shared__ u64 wl[384];          // [0..127]=W2 [128..383]=W3 (128 rows)
    __shared__ int gT[64], gF[64];
    {
        const int t = threadIdx.x;
        if (t < 64) {
            u64 h, l;
            pack_row(W2 + t * 64, false, false, h, l);
            wl[2 * t] = h; wl[2 * t + 1] = l;
        } else if (t < 192) {
            const int r = t - 64;
            u64 h, l;
            pack_row(W3 + r * 64, false, false, h, l);
            wl[128 + 2 * r] = h; wl[129 + 2 * r] = l;
        } else {
            const int c = t - 192;
            float a, b;
            affine_from_stats(stats, 64 + c, scale, gamma, beta, c, a, b);
            bool fl;
            gT[c] = make_thresh(a, b, fl);
            gF[c] = fl ? 1 : 0;
        }
    }
    __syncthreads();

    const int lane = threadIdx.x & 63;
    const int wib = threadIdx.x >> 6;
    const int wid = (blockIdx.x << 2) | wib;        // row m = wid
    const int T = gT[lane];
    const u64 w2P = gF[lane] ? wl[2 * lane + 1] : wl[2 * lane];   // flip: swap
    const u64 w2N = gF[lane] ? wl[2 * lane] : wl[2 * lane + 1];
    const u64 w3aP = wl[128 + 2 * lane], w3aN = wl[129 + 2 * lane];
    const u64 w3bP = wl[128 + 2 * (lane + 64)], w3bN = wl[129 + 2 * (lane + 64)];

    const u32 a32 = ((const u32*)A2)[(size_t)wid * 64 + lane];  // 32 pos x 2 u32
    int sda0 = 0, sqa0 = 0, sdb0 = 0, sqb0 = 0;
    int sda1 = 0, sqa1 = 0, sdb1 = 0, sqb1 = 0;
    int maxa = -127, mina = 127, maxb = -127, minb = 127;
    #pragma unroll
    for (int pp = 0; pp < 16; ++pp) {
        {
            const int p = 2 * pp;
            u32 lo = __builtin_amdgcn_readlane(a32, 2 * p);
            u32 hi = __builtin_amdgcn_readlane(a32, 2 * p + 1);
            u64 A = ((u64)hi << 32) | lo;
            int d2 = __popcll(A & w2P) - __popcll(A & w2N);
            u64 A3 = __ballot(d2 >= T);
            int da = __popcll(A3 & w3aP) - __popcll(A3 & w3aN);
            int db = __popcll(A3 & w3bP) - __popcll(A3 & w3bN);
            sda0 += da; sqa0 += da * da; sdb0 += db; sqb0 += db * db;
            maxa = max(maxa, da); mina = min(mina, da);
            maxb = max(maxb, db); minb = min(minb, db);
        }
        {
            const int p = 2 * pp + 1;
            u32 lo = __builtin_amdgcn_readlane(a32, 2 * p);
            u32 hi = __builtin_amdgcn_readlane(a32, 2 * p + 1);
            u64 A = ((u64)hi << 32) | lo;
            int d2 = __popcll(A & w2P) - __popcll(A & w2N);
            u64 A3 = __ballot(d2 >= T);
            int da = __popcll(A3 & w3aP) - __popcll(A3 & w3aN);
            int db = __popcll(A3 & w3bP) - __popcll(A3 & w3bN);
            sda1 += da; sqa1 += da * da; sdb1 += db; sqb1 += db * db;
            maxa = max(maxa, da); mina = min(mina, da);
            maxb = max(maxb, db); minb = min(minb, db);
        }
    }
    dmm[wid * 128 + lane]      = (short)((maxa & 0xFF) | ((mina & 0xFF) << 8));
    dmm[wid * 128 + 64 + lane] = (short)((maxb & 0xFF) | ((minb & 0xFF) << 8));

    __shared__ int rda[4][64], rqa[4][64], rdb[4][64], rqb[4][64];
    rda[wib][lane] = sda0 + sda1; rqa[wib][lane] = sqa0 + sqa1;
    rdb[wib][lane] = sdb0 + sdb1; rqb[wib][lane] = sqb0 + sqb1;
    __syncthreads();
    if (threadIdx.x < 64) {
        const int rep = (blockIdx.x & (NREP - 1)) * 256;
        int tda = rda[0][lane] + rda[1][lane] + rda[2][lane] + rda[3][lane];
        int tqa = rqa[0][lane] + rqa[1][lane] + rqa[2][lane] + rqa[3][lane];
        int tdb = rdb[0][lane] + rdb[1][lane] + rdb[2][lane] + rdb[3][lane];
        int tqb = rqb[0][lane] + rqb[1][lane] + rqb[2][lane] + rqb[3][lane];
        atomicAdd(&stats[rep + 128 + lane], pack_stats(tda, tqa));
        atomicAdd(&stats[rep + 192 + lane], pack_stats(tdb, tqb));
    }
}

// -------- K4: v = a*(a>=0?dmax:dmin)+b, ReLU, write [8192,128] --------------
__global__ void __launch_bounds__(512) k4_out(
    const short* __restrict__ dmm, const float* __restrict__ scale,
    const float* __restrict__ gamma, const float* __restrict__ beta,
    const u64* __restrict__ stats, float* __restrict__ out) {
    __shared__ float sa[128], sb[128];
    if (threadIdx.x < 128)
        affine_from_stats(stats, 128 + threadIdx.x, scale, gamma, beta,
                          threadIdx.x, sa[threadIdx.x], sb[threadIdx.x]);
    __syncthreads();
    const int idx = blockIdx.x * 512 + threadIdx.x;   // m*128 + o
    const int o = idx & 127;
    short pk = dmm[idx];
    int mx = (signed char)(pk & 0xFF);
    int mn = (signed char)((pk >> 8) & 0xFF);
    float a = sa[o], b = sb[o];
    float v = fmaf(a, (float)(a >= 0.f ? mx : mn), b);
    out[idx] = fmaxf(v, 0.f);
}

extern "C" void kernel_launch(void* const* d_in, const int* in_sizes, int n_in,
                              void* d_out, int out_size, void* d_ws, size_t ws_size,
                              hipStream_t stream) {
    const float* agg = (const float*)d_in[0];
    const float* W1 = (const float*)d_in[1];
    const float* s1 = (const float*)d_in[2];
    const float* g1 = (const float*)d_in[3];
    const float* b1 = (const float*)d_in[4];
    const float* W2 = (const float*)d_in[5];
    const float* s2 = (const float*)d_in[6];
    const float* g2 = (const float*)d_in[7];
    const float* b2 = (const float*)d_in[8];
    const float* W3 = (const float*)d_in[9];
    const float* s3 = (const float*)d_in[10];
    const float* g3 = (const float*)d_in[11];
    const float* b3 = (const float*)d_in[12];
    float* out = (float*)d_out;

    char* ws = (char*)d_ws;
    u64* stats = (u64*)ws;                                     // 32 KB
    ulonglong2* A1 = (ulonglong2*)(ws + 65536);                // 4 MB
    u64* A2 = (u64*)(ws + 65536 + (size_t)P_TOTAL * 16);       // 2 MB
    short* dmm = (short*)(ws + 65536 + (size_t)P_TOTAL * 24);  // 2 MB

    k_zero<<<NREP, 256, 0, stream>>>(stats);
    k1_pack_stats<<<2048, 256, 0, stream>>>((const float4*)agg, W1, A1, stats);
    k2_bin1_stats2<<<2048, 256, 0, stream>>>(A1, W1, W2, s1, g1, b1, A2, stats);
    k3_bin2_stats3<<<2048, 256, 0, stream>>>(A2, W2, W3, s2, g2, b2, dmm, stats);
    k4_out<<<2048, 512, 0, stream>>>(dmm, s3, g3, b3, stats, out);
}